// Round 1
// baseline (1601.942 us; speedup 1.0000x reference)
//
#include <hip/hip_runtime.h>
#include <stdint.h>

#define BB 4
#define NN 32768
#define PRE 4096
#define POST 512
#define NMS_TH 0.7f

typedef unsigned long long u64;
typedef unsigned int u32;

__device__ __forceinline__ u32 orderable(float f) {
  u32 u = __float_as_uint(f);
  return (u & 0x80000000u) ? ~u : (u | 0x80000000u);
}

// Per-point: score = max over 3 classes, label = first argmax, sort key.
__global__ void score_kernel(const float* __restrict__ cls, float* __restrict__ scores,
                             int* __restrict__ labels, u64* __restrict__ keys) {
  int g = blockIdx.x * blockDim.x + threadIdx.x;
  if (g >= BB * NN) return;
  const float* c = cls + (size_t)g * 3;
  float s = c[0]; int l = 0;
  float c1 = c[1], c2 = c[2];
  if (c1 > s) { s = c1; l = 1; }
  if (c2 > s) { s = c2; l = 2; }
  scores[g] = s;
  labels[g] = l;
  int n = g & (NN - 1);
  keys[g] = ((u64)orderable(s) << 32) | (u32)(~(u32)n);
}

// Full descending bitonic sort of one 4096-chunk in LDS.
__global__ __launch_bounds__(512) void sort4k_kernel(u64* keys) {
  __shared__ u64 sh[4096];
  u64* base = keys + (size_t)blockIdx.x * 4096;
  for (int t = threadIdx.x; t < 4096; t += 512) sh[t] = base[t];
  __syncthreads();
  for (int k = 2; k <= 4096; k <<= 1) {
    for (int j = k >> 1; j > 0; j >>= 1) {
      for (int t = threadIdx.x; t < 4096; t += 512) {
        int p = t ^ j;
        if (p > t) {
          u64 a = sh[t], b = sh[p];
          bool desc = ((t & k) == 0);
          if (desc ? (a < b) : (a > b)) { sh[t] = b; sh[p] = a; }
        }
      }
      __syncthreads();
    }
  }
  for (int t = threadIdx.x; t < 4096; t += 512) base[t] = sh[t];
}

// Merge two descending 4096-lists; emit top-4096 descending of the union.
// dynamic LDS: 8192 u64 = 64 KiB
__global__ __launch_bounds__(1024) void merge_kernel(const u64* __restrict__ in, u64* __restrict__ out,
                                                     int pairs, int inStride, int outStride) {
  extern __shared__ u64 sh[];
  int b = blockIdx.x / pairs, pr = blockIdx.x % pairs;
  const u64* inA = in + (size_t)b * inStride + (size_t)pr * 8192;
  for (int t = threadIdx.x; t < 8192; t += 1024)
    sh[t] = (t < 4096) ? inA[t] : inA[12287 - t];  // second list reversed -> bitonic
  __syncthreads();
  for (int j = 4096; j > 0; j >>= 1) {
    for (int t = threadIdx.x; t < 8192; t += 1024) {
      int p = t ^ j;
      if (p > t) {
        u64 a = sh[t], bv = sh[p];
        if (a < bv) { sh[t] = bv; sh[p] = a; }
      }
    }
    __syncthreads();
  }
  u64* o = out + (size_t)b * outStride + (size_t)pr * 4096;
  for (int t = threadIdx.x; t < 4096; t += 1024) o[t] = sh[t];
}

// Gather top-4096 boxes; precompute x1/x2/y1/y2/area SoA.
__global__ void gather_kernel(const u64* __restrict__ keys, const float* __restrict__ boxes,
                              const float* __restrict__ scores, const int* __restrict__ labels,
                              float* __restrict__ topBox,
                              float* __restrict__ X1, float* __restrict__ Y1,
                              float* __restrict__ X2, float* __restrict__ Y2,
                              float* __restrict__ AR,
                              float* __restrict__ topS, int* __restrict__ topL) {
  int g = blockIdx.x * blockDim.x + threadIdx.x;
  if (g >= BB * PRE) return;
  int b = g >> 12;
  u64 key = keys[g];
  u32 n = ~(u32)key;
  size_t src = (size_t)b * NN + n;
  const float* bx = boxes + src * 7;
  float x = bx[0], y = bx[1], dx = bx[3], dy = bx[4];
  float* tb = topBox + (size_t)g * 7;
#pragma unroll
  for (int c = 0; c < 7; ++c) tb[c] = bx[c];
  X1[g] = x - 0.5f * dx; X2[g] = x + 0.5f * dx;   // 0.5*dx exact -> contraction-safe
  Y1[g] = y - 0.5f * dy; Y2[g] = y + 0.5f * dy;
  AR[g] = dx * dy;
  topS[g] = scores[src];
  topL[g] = labels[src];
}

// Suppression bitmask: word (b, row i, w) bit j = iou(i, w*64+j) > 0.7
__global__ void mask_kernel(const float* __restrict__ X1, const float* __restrict__ Y1,
                            const float* __restrict__ X2, const float* __restrict__ Y2,
                            const float* __restrict__ AR, u64* __restrict__ mask) {
  int gw = blockIdx.x * blockDim.x + threadIdx.x;
  if (gw >= BB * PRE * 64) return;
  int b = gw >> 18;            // / (4096*64)
  int rem = gw & (PRE * 64 - 1);
  int i = rem >> 6;
  int w = rem & 63;
  int rowBase = (b << 12) + i;
  float x1 = X1[rowBase], y1 = Y1[rowBase], x2 = X2[rowBase], y2 = Y2[rowBase], ar = AR[rowBase];
  int colBase = (b << 12) + (w << 6);
  u64 bits = 0;
#pragma unroll 4
  for (int j = 0; j < 64; ++j) {
    int cb = colBase + j;
    float ix = fminf(x2, X2[cb]) - fmaxf(x1, X1[cb]); ix = fmaxf(0.0f, ix);
    float iy = fminf(y2, Y2[cb]) - fmaxf(y1, Y1[cb]); iy = fmaxf(0.0f, iy);
    float inter = ix * iy;
    float denom = ((ar + AR[cb]) - inter) + 1e-6f;
    if (inter / denom > NMS_TH) bits |= (1ULL << j);
  }
  mask[gw] = bits;
}

// Greedy sequential scan: one 64-lane wave per batch, remv word per lane in reg.
__global__ __launch_bounds__(64) void scan_kernel(const u64* __restrict__ mask,
                                                  int* __restrict__ keepIdx,
                                                  int* __restrict__ keepCount) {
  int b = blockIdx.x;
  int lane = threadIdx.x;
  const u64* m = mask + (size_t)b * PRE * 64;
  u64 r = 0;
  int nk = 0;
  for (int i = 0; i < PRE; ++i) {
    u64 mi = m[(size_t)i * 64 + lane];          // prefetch (independent of r)
    int bit = i & 63;
    int sup = (int)((r >> bit) & 1ULL);
    sup = __shfl(sup, i >> 6, 64);              // broadcast from owning lane
    if (!sup) {
      r |= mi;
      if (nk < POST && lane == 0) keepIdx[b * POST + nk] = i;
      ++nk;
    }
  }
  if (lane == 0) keepCount[b] = nk < POST ? nk : POST;
}

// Write all 512 slots per batch: kept -> data, empty -> 0 (label 1).
__global__ void output_kernel(const int* __restrict__ keepIdx, const int* __restrict__ keepCount,
                              const float* __restrict__ topBox, const float* __restrict__ topS,
                              const int* __restrict__ topL, float* __restrict__ out) {
  int g = blockIdx.x * blockDim.x + threadIdx.x;
  if (g >= BB * POST) return;
  int b = g >> 9, s = g & (POST - 1);
  float* outR = out;                       // BB*POST*7
  float* outS = out + BB * POST * 7;       // +14336
  float* outL = outS + BB * POST;          // +2048
  int cnt = keepCount[b];
  if (s < cnt) {
    int i = keepIdx[g];
    const float* tb = topBox + ((size_t)(b << 12) + i) * 7;
#pragma unroll
    for (int c = 0; c < 7; ++c) outR[(size_t)g * 7 + c] = tb[c];
    outS[g] = topS[(b << 12) + i];
    outL[g] = (float)(topL[(b << 12) + i] + 1);
  } else {
#pragma unroll
    for (int c = 0; c < 7; ++c) outR[(size_t)g * 7 + c] = 0.0f;
    outS[g] = 0.0f;
    outL[g] = 1.0f;
  }
}

extern "C" void kernel_launch(void* const* d_in, const int* in_sizes, int n_in,
                              void* d_out, int out_size, void* d_ws, size_t ws_size,
                              hipStream_t stream) {
  const float* boxes = (const float*)d_in[0];   // (4,32768,7)
  const float* cls   = (const float*)d_in[1];   // (4,32768,3)
  float* out = (float*)d_out;

  // ---- workspace carve-up (~12.6 MB) ----
  char* p = (char*)d_ws;
  auto take = [&](size_t bytes) { char* r = p; p += (bytes + 255) & ~(size_t)255; return (void*)r; };
  float* scores  = (float*)take((size_t)BB * NN * 4);
  int*   labels  = (int*)  take((size_t)BB * NN * 4);
  u64*   keysA   = (u64*)  take((size_t)BB * NN * 8);
  u64*   keysB   = (u64*)  take((size_t)BB * NN * 8);
  float* topBox  = (float*)take((size_t)BB * PRE * 7 * 4);
  float* X1      = (float*)take((size_t)BB * PRE * 4);
  float* Y1      = (float*)take((size_t)BB * PRE * 4);
  float* X2      = (float*)take((size_t)BB * PRE * 4);
  float* Y2      = (float*)take((size_t)BB * PRE * 4);
  float* AR      = (float*)take((size_t)BB * PRE * 4);
  float* topS    = (float*)take((size_t)BB * PRE * 4);
  int*   topL    = (int*)  take((size_t)BB * PRE * 4);
  u64*   maskBuf = (u64*)  take((size_t)BB * PRE * 64 * 8);
  int*   keepIdx = (int*)  take((size_t)BB * POST * 4);
  int*   keepCnt = (int*)  take((size_t)BB * 4);

  score_kernel<<<(BB * NN + 255) / 256, 256, 0, stream>>>(cls, scores, labels, keysA);
  sort4k_kernel<<<BB * 8, 512, 0, stream>>>(keysA);
  merge_kernel<<<BB * 4, 1024, 65536, stream>>>(keysA, keysB, 4, 32768, 16384);
  merge_kernel<<<BB * 2, 1024, 65536, stream>>>(keysB, keysA, 2, 16384, 8192);
  merge_kernel<<<BB * 1, 1024, 65536, stream>>>(keysA, keysB, 1, 8192, 4096);
  gather_kernel<<<(BB * PRE + 255) / 256, 256, 0, stream>>>(keysB, boxes, scores, labels,
                                                            topBox, X1, Y1, X2, Y2, AR, topS, topL);
  mask_kernel<<<(BB * PRE * 64 + 255) / 256, 256, 0, stream>>>(X1, Y1, X2, Y2, AR, maskBuf);
  scan_kernel<<<BB, 64, 0, stream>>>(maskBuf, keepIdx, keepCnt);
  output_kernel<<<(BB * POST + 255) / 256, 256, 0, stream>>>(keepIdx, keepCnt, topBox, topS, topL, out);
}

// Round 2
// 475.499 us; speedup vs baseline: 3.3690x; 3.3690x over previous
//
#include <hip/hip_runtime.h>
#include <stdint.h>

#define BB 4
#define NN 32768
#define PRE 4096
#define POST 512
#define NMS_TH 0.7f

typedef unsigned long long u64;
typedef unsigned int u32;

__device__ __forceinline__ u32 orderable(float f) {
  u32 u = __float_as_uint(f);
  return (u & 0x80000000u) ? ~u : (u | 0x80000000u);
}

// Per-point: score = max over 3 classes, label = first argmax, sort key.
__global__ void score_kernel(const float* __restrict__ cls, float* __restrict__ scores,
                             int* __restrict__ labels, u64* __restrict__ keys) {
  int g = blockIdx.x * blockDim.x + threadIdx.x;
  if (g >= BB * NN) return;
  const float* c = cls + (size_t)g * 3;
  float s = c[0]; int l = 0;
  float c1 = c[1], c2 = c[2];
  if (c1 > s) { s = c1; l = 1; }
  if (c2 > s) { s = c2; l = 2; }
  scores[g] = s;
  labels[g] = l;
  int n = g & (NN - 1);
  keys[g] = ((u64)orderable(s) << 32) | (u32)(~(u32)n);
}

// Full descending bitonic sort of one 4096-chunk in LDS.
__global__ __launch_bounds__(512) void sort4k_kernel(u64* keys) {
  __shared__ u64 sh[4096];
  u64* base = keys + (size_t)blockIdx.x * 4096;
  for (int t = threadIdx.x; t < 4096; t += 512) sh[t] = base[t];
  __syncthreads();
  for (int k = 2; k <= 4096; k <<= 1) {
    for (int j = k >> 1; j > 0; j >>= 1) {
      for (int t = threadIdx.x; t < 4096; t += 512) {
        int p = t ^ j;
        if (p > t) {
          u64 a = sh[t], b = sh[p];
          bool desc = ((t & k) == 0);
          if (desc ? (a < b) : (a > b)) { sh[t] = b; sh[p] = a; }
        }
      }
      __syncthreads();
    }
  }
  for (int t = threadIdx.x; t < 4096; t += 512) base[t] = sh[t];
}

// Merge two descending 4096-lists; emit top-4096 descending of the union.
// dynamic LDS: 8192 u64 = 64 KiB
__global__ __launch_bounds__(1024) void merge_kernel(const u64* __restrict__ in, u64* __restrict__ out,
                                                     int pairs, int inStride, int outStride) {
  extern __shared__ u64 sh[];
  int b = blockIdx.x / pairs, pr = blockIdx.x % pairs;
  const u64* inA = in + (size_t)b * inStride + (size_t)pr * 8192;
  for (int t = threadIdx.x; t < 8192; t += 1024)
    sh[t] = (t < 4096) ? inA[t] : inA[12287 - t];  // second list reversed -> bitonic
  __syncthreads();
  for (int j = 4096; j > 0; j >>= 1) {
    for (int t = threadIdx.x; t < 8192; t += 1024) {
      int p = t ^ j;
      if (p > t) {
        u64 a = sh[t], bv = sh[p];
        if (a < bv) { sh[t] = bv; sh[p] = a; }
      }
    }
    __syncthreads();
  }
  u64* o = out + (size_t)b * outStride + (size_t)pr * 4096;
  for (int t = threadIdx.x; t < 4096; t += 1024) o[t] = sh[t];
}

// Gather top-4096 boxes; precompute x1/x2/y1/y2/area SoA.
__global__ void gather_kernel(const u64* __restrict__ keys, const float* __restrict__ boxes,
                              const float* __restrict__ scores, const int* __restrict__ labels,
                              float* __restrict__ topBox,
                              float* __restrict__ X1, float* __restrict__ Y1,
                              float* __restrict__ X2, float* __restrict__ Y2,
                              float* __restrict__ AR,
                              float* __restrict__ topS, int* __restrict__ topL) {
  int g = blockIdx.x * blockDim.x + threadIdx.x;
  if (g >= BB * PRE) return;
  int b = g >> 12;
  u64 key = keys[g];
  u32 n = ~(u32)key;
  size_t src = (size_t)b * NN + n;
  const float* bx = boxes + src * 7;
  float x = bx[0], y = bx[1], dx = bx[3], dy = bx[4];
  float* tb = topBox + (size_t)g * 7;
#pragma unroll
  for (int c = 0; c < 7; ++c) tb[c] = bx[c];
  X1[g] = x - 0.5f * dx; X2[g] = x + 0.5f * dx;   // 0.5*dx exact -> contraction-safe
  Y1[g] = y - 0.5f * dy; Y2[g] = y + 0.5f * dy;
  AR[g] = dx * dy;
  topS[g] = scores[src];
  topL[g] = labels[src];
}

// Suppression bitmask: word (b, row i, w) bit j = iou(i, w*64+j) > 0.7
// Triangular skip: words w < i>>6 are never read by the scan (bits j <= i of
// a row OR'd at step i can only affect decisions for boxes <= i, which are
// already made). Skip computing/writing them -> half the work.
__global__ void mask_kernel(const float* __restrict__ X1, const float* __restrict__ Y1,
                            const float* __restrict__ X2, const float* __restrict__ Y2,
                            const float* __restrict__ AR, u64* __restrict__ mask) {
  int gw = blockIdx.x * blockDim.x + threadIdx.x;
  if (gw >= BB * PRE * 64) return;
  int b = gw >> 18;            // / (4096*64)
  int rem = gw & (PRE * 64 - 1);
  int i = rem >> 6;
  int w = rem & 63;
  if (w < (i >> 6)) return;    // strictly-below-diagonal word: dead, skip
  int rowBase = (b << 12) + i;
  float x1 = X1[rowBase], y1 = Y1[rowBase], x2 = X2[rowBase], y2 = Y2[rowBase], ar = AR[rowBase];
  int colBase = (b << 12) + (w << 6);
  u64 bits = 0;
#pragma unroll 4
  for (int j = 0; j < 64; ++j) {
    int cb = colBase + j;
    float ix = fminf(x2, X2[cb]) - fmaxf(x1, X1[cb]); ix = fmaxf(0.0f, ix);
    float iy = fminf(y2, Y2[cb]) - fmaxf(y1, Y1[cb]); iy = fmaxf(0.0f, iy);
    float inter = ix * iy;
    float denom = ((ar + AR[cb]) - inter) + 1e-6f;
    if (inter / denom > NMS_TH) bits |= (1ULL << j);
  }
  mask[gw] = bits;
}

// Greedy sequential scan: one 64-lane wave per batch, remv word per lane in reg.
// (a) 16-deep statically-indexed prefetch ring hides row-load latency;
// (b) early exit once 512 boxes are kept (later keeps are dead in the reference).
#define SCAN_D 16
__global__ __launch_bounds__(64) void scan_kernel(const u64* __restrict__ mask,
                                                  int* __restrict__ keepIdx,
                                                  int* __restrict__ keepCount) {
  int b = blockIdx.x;
  int lane = threadIdx.x;
  const u64* m = mask + (size_t)b * PRE * 64 + lane;
  u64 buf[SCAN_D];
#pragma unroll
  for (int k = 0; k < SCAN_D; ++k) buf[k] = m[(size_t)k * 64];
  u64 r = 0;
  int nk = 0;
  for (int ib = 0; ib < PRE; ib += SCAN_D) {
#pragma unroll
    for (int k = 0; k < SCAN_D; ++k) {
      int i = ib + k;
      u64 mi = buf[k];
      int ip = i + SCAN_D;
      if (ip < PRE) buf[k] = m[(size_t)ip * 64];   // prefetch, independent of r
      int bit = i & 63;
      int sup = (int)((r >> bit) & 1ULL);
      sup = __shfl(sup, i >> 6, 64);               // broadcast from owning lane
      if (!sup) {
        r |= mi;
        if (nk < POST && lane == 0) keepIdx[b * POST + nk] = i;
        ++nk;
      }
    }
    if (nk >= POST) break;                         // first 512 keeps found: done
  }
  if (lane == 0) keepCount[b] = nk < POST ? nk : POST;
}

// Write all 512 slots per batch: kept -> data, empty -> 0 (label 1).
__global__ void output_kernel(const int* __restrict__ keepIdx, const int* __restrict__ keepCount,
                              const float* __restrict__ topBox, const float* __restrict__ topS,
                              const int* __restrict__ topL, float* __restrict__ out) {
  int g = blockIdx.x * blockDim.x + threadIdx.x;
  if (g >= BB * POST) return;
  int b = g >> 9, s = g & (POST - 1);
  float* outR = out;                       // BB*POST*7
  float* outS = out + BB * POST * 7;       // +14336
  float* outL = outS + BB * POST;          // +2048
  int cnt = keepCount[b];
  if (s < cnt) {
    int i = keepIdx[g];
    const float* tb = topBox + ((size_t)(b << 12) + i) * 7;
#pragma unroll
    for (int c = 0; c < 7; ++c) outR[(size_t)g * 7 + c] = tb[c];
    outS[g] = topS[(b << 12) + i];
    outL[g] = (float)(topL[(b << 12) + i] + 1);
  } else {
#pragma unroll
    for (int c = 0; c < 7; ++c) outR[(size_t)g * 7 + c] = 0.0f;
    outS[g] = 0.0f;
    outL[g] = 1.0f;
  }
}

extern "C" void kernel_launch(void* const* d_in, const int* in_sizes, int n_in,
                              void* d_out, int out_size, void* d_ws, size_t ws_size,
                              hipStream_t stream) {
  const float* boxes = (const float*)d_in[0];   // (4,32768,7)
  const float* cls   = (const float*)d_in[1];   // (4,32768,3)
  float* out = (float*)d_out;

  // ---- workspace carve-up (~12.6 MB) ----
  char* p = (char*)d_ws;
  auto take = [&](size_t bytes) { char* r = p; p += (bytes + 255) & ~(size_t)255; return (void*)r; };
  float* scores  = (float*)take((size_t)BB * NN * 4);
  int*   labels  = (int*)  take((size_t)BB * NN * 4);
  u64*   keysA   = (u64*)  take((size_t)BB * NN * 8);
  u64*   keysB   = (u64*)  take((size_t)BB * NN * 8);
  float* topBox  = (float*)take((size_t)BB * PRE * 7 * 4);
  float* X1      = (float*)take((size_t)BB * PRE * 4);
  float* Y1      = (float*)take((size_t)BB * PRE * 4);
  float* X2      = (float*)take((size_t)BB * PRE * 4);
  float* Y2      = (float*)take((size_t)BB * PRE * 4);
  float* AR      = (float*)take((size_t)BB * PRE * 4);
  float* topS    = (float*)take((size_t)BB * PRE * 4);
  int*   topL    = (int*)  take((size_t)BB * PRE * 4);
  u64*   maskBuf = (u64*)  take((size_t)BB * PRE * 64 * 8);
  int*   keepIdx = (int*)  take((size_t)BB * POST * 4);
  int*   keepCnt = (int*)  take((size_t)BB * 4);

  score_kernel<<<(BB * NN + 255) / 256, 256, 0, stream>>>(cls, scores, labels, keysA);
  sort4k_kernel<<<BB * 8, 512, 0, stream>>>(keysA);
  merge_kernel<<<BB * 4, 1024, 65536, stream>>>(keysA, keysB, 4, 32768, 16384);
  merge_kernel<<<BB * 2, 1024, 65536, stream>>>(keysB, keysA, 2, 16384, 8192);
  merge_kernel<<<BB * 1, 1024, 65536, stream>>>(keysA, keysB, 1, 8192, 4096);
  gather_kernel<<<(BB * PRE + 255) / 256, 256, 0, stream>>>(keysB, boxes, scores, labels,
                                                            topBox, X1, Y1, X2, Y2, AR, topS, topL);
  mask_kernel<<<(BB * PRE * 64 + 255) / 256, 256, 0, stream>>>(X1, Y1, X2, Y2, AR, maskBuf);
  scan_kernel<<<BB, 64, 0, stream>>>(maskBuf, keepIdx, keepCnt);
  output_kernel<<<(BB * POST + 255) / 256, 256, 0, stream>>>(keepIdx, keepCnt, topBox, topS, topL, out);
}

// Round 3
// 323.017 us; speedup vs baseline: 4.9593x; 1.4721x over previous
//
#include <hip/hip_runtime.h>
#include <stdint.h>

#define BB 4
#define NN 32768
#define PRE 4096
#define POST 512
#define NMS_TH 0.7f

typedef unsigned long long u64;
typedef unsigned int u32;

__device__ __forceinline__ u32 orderable(float f) {
  u32 u = __float_as_uint(f);
  return (u & 0x80000000u) ? ~u : (u | 0x80000000u);
}

// Per-point: score = max over 3 classes, label = first argmax, sort key.
__global__ void score_kernel(const float* __restrict__ cls, float* __restrict__ scores,
                             int* __restrict__ labels, u64* __restrict__ keys) {
  int g = blockIdx.x * blockDim.x + threadIdx.x;
  if (g >= BB * NN) return;
  const float* c = cls + (size_t)g * 3;
  float s = c[0]; int l = 0;
  float c1 = c[1], c2 = c[2];
  if (c1 > s) { s = c1; l = 1; }
  if (c2 > s) { s = c2; l = 2; }
  scores[g] = s;
  labels[g] = l;
  int n = g & (NN - 1);
  keys[g] = ((u64)orderable(s) << 32) | (u32)(~(u32)n);
}

// Full descending bitonic sort of one 4096-chunk in LDS.
__global__ __launch_bounds__(512) void sort4k_kernel(u64* keys) {
  __shared__ u64 sh[4096];
  u64* base = keys + (size_t)blockIdx.x * 4096;
  for (int t = threadIdx.x; t < 4096; t += 512) sh[t] = base[t];
  __syncthreads();
  for (int k = 2; k <= 4096; k <<= 1) {
    for (int j = k >> 1; j > 0; j >>= 1) {
      for (int t = threadIdx.x; t < 4096; t += 512) {
        int p = t ^ j;
        if (p > t) {
          u64 a = sh[t], b = sh[p];
          bool desc = ((t & k) == 0);
          if (desc ? (a < b) : (a > b)) { sh[t] = b; sh[p] = a; }
        }
      }
      __syncthreads();
    }
  }
  for (int t = threadIdx.x; t < 4096; t += 512) base[t] = sh[t];
}

// Merge two descending 4096-lists; emit top-4096 descending of the union.
// dynamic LDS: 8192 u64 = 64 KiB
__global__ __launch_bounds__(1024) void merge_kernel(const u64* __restrict__ in, u64* __restrict__ out,
                                                     int pairs, int inStride, int outStride) {
  extern __shared__ u64 sh[];
  int b = blockIdx.x / pairs, pr = blockIdx.x % pairs;
  const u64* inA = in + (size_t)b * inStride + (size_t)pr * 8192;
  for (int t = threadIdx.x; t < 8192; t += 1024)
    sh[t] = (t < 4096) ? inA[t] : inA[12287 - t];  // second list reversed -> bitonic
  __syncthreads();
  for (int j = 4096; j > 0; j >>= 1) {
    for (int t = threadIdx.x; t < 8192; t += 1024) {
      int p = t ^ j;
      if (p > t) {
        u64 a = sh[t], bv = sh[p];
        if (a < bv) { sh[t] = bv; sh[p] = a; }
      }
    }
    __syncthreads();
  }
  u64* o = out + (size_t)b * outStride + (size_t)pr * 4096;
  for (int t = threadIdx.x; t < 4096; t += 1024) o[t] = sh[t];
}

// Gather top-4096 boxes; precompute x1/x2/y1/y2/area SoA.
__global__ void gather_kernel(const u64* __restrict__ keys, const float* __restrict__ boxes,
                              const float* __restrict__ scores, const int* __restrict__ labels,
                              float* __restrict__ topBox,
                              float* __restrict__ X1, float* __restrict__ Y1,
                              float* __restrict__ X2, float* __restrict__ Y2,
                              float* __restrict__ AR,
                              float* __restrict__ topS, int* __restrict__ topL) {
  int g = blockIdx.x * blockDim.x + threadIdx.x;
  if (g >= BB * PRE) return;
  int b = g >> 12;
  u64 key = keys[g];
  u32 n = ~(u32)key;
  size_t src = (size_t)b * NN + n;
  const float* bx = boxes + src * 7;
  float x = bx[0], y = bx[1], dx = bx[3], dy = bx[4];
  float* tb = topBox + (size_t)g * 7;
#pragma unroll
  for (int c = 0; c < 7; ++c) tb[c] = bx[c];
  X1[g] = x - 0.5f * dx; X2[g] = x + 0.5f * dx;   // 0.5*dx exact -> contraction-safe
  Y1[g] = y - 0.5f * dy; Y2[g] = y + 0.5f * dy;
  AR[g] = dx * dy;
  topS[g] = scores[src];
  topL[g] = labels[src];
}

// Suppression bitmask: word (b, row i, w) bit j = iou(i, w*64+j) > 0.7
// Triangular skip: words w < i>>6 are never read by the scan. Diagonal words
// (w == i>>6) are additionally written to a contiguous sidecar for the scan's
// group-decision broadcast.
__global__ void mask_kernel(const float* __restrict__ X1, const float* __restrict__ Y1,
                            const float* __restrict__ X2, const float* __restrict__ Y2,
                            const float* __restrict__ AR, u64* __restrict__ mask,
                            u64* __restrict__ diag) {
  int gw = blockIdx.x * blockDim.x + threadIdx.x;
  if (gw >= BB * PRE * 64) return;
  int b = gw >> 18;            // / (4096*64)
  int rem = gw & (PRE * 64 - 1);
  int i = rem >> 6;
  int w = rem & 63;
  if (w < (i >> 6)) return;    // strictly-below-diagonal word: dead, skip
  int rowBase = (b << 12) + i;
  float x1 = X1[rowBase], y1 = Y1[rowBase], x2 = X2[rowBase], y2 = Y2[rowBase], ar = AR[rowBase];
  int colBase = (b << 12) + (w << 6);
  u64 bits = 0;
#pragma unroll 4
  for (int j = 0; j < 64; ++j) {
    int cb = colBase + j;
    float ix = fminf(x2, X2[cb]) - fmaxf(x1, X1[cb]); ix = fmaxf(0.0f, ix);
    float iy = fminf(y2, Y2[cb]) - fmaxf(y1, Y1[cb]); iy = fmaxf(0.0f, iy);
    float inter = ix * iy;
    float denom = ((ar + AR[cb]) - inter) + 1e-6f;
    if (inter / denom > NMS_TH) bits |= (1ULL << j);
  }
  mask[gw] = bits;
  if (w == (i >> 6)) diag[rowBase] = bits;
}

// Greedy scan, group-of-64 formulation. One 64-lane wave per batch.
// Lane l owns remv word l (boxes [64l,64l+64)). Per group g:
//   1. sup_word = shfl(r, g)            -- one broadcast per GROUP
//   2. all lanes redundantly run the 64-step bit recurrence using the diag
//      words (broadcast via independent shfls, batches of 8): pure VALU,
//      no memory, no branches on the critical path.
//   3. remv update: r |= OR of row words (lane's column) for kept rows;
//      64 coalesced loads issued up-front, gated by uniform keep_word.
// Keep words go to LDS; expanded to keepIdx once at the end (no global
// stores in the loop -> compiler can use counted vmcnt on the row loads).
__global__ __launch_bounds__(64) void scan_kernel(const u64* __restrict__ mask,
                                                  const u64* __restrict__ diag,
                                                  int* __restrict__ keepIdx,
                                                  int* __restrict__ keepCount) {
  __shared__ u64 kwLDS[64];
  int b = blockIdx.x;
  int lane = threadIdx.x;
  const u64* m = mask + (size_t)b * PRE * 64;
  const u64* dg = diag + (size_t)b * PRE;
  kwLDS[lane] = 0;
  __syncthreads();
  u64 r = 0;
  int nk = 0;
  for (int g = 0; g < PRE / 64; ++g) {
    // lane t holds diag value for box 64g+t
    u64 d_l = dg[g * 64 + lane];
    // row words for the remv update: rowv[t] = m[(64g+t)*64 + lane]
    u64 rowv[64];
#pragma unroll
    for (int t = 0; t < 64; ++t) rowv[t] = m[((size_t)(g * 64 + t)) * 64 + lane];
    // suppression state of this group's boxes from all earlier groups
    u64 sup_word = __shfl(r, g, 64);
    u64 keep_word = 0;
#pragma unroll
    for (int s = 0; s < 8; ++s) {
      u64 dk[8];
#pragma unroll
      for (int t = 0; t < 8; ++t) dk[t] = __shfl(d_l, s * 8 + t, 64);  // independent
#pragma unroll
      for (int t = 0; t < 8; ++t) {
        int k = s * 8 + t;
        u64 bit = (sup_word >> k) & 1ULL;
        keep_word |= (bit ^ 1ULL) << k;
        u64 mk = dk[t] & ~((2ULL << k) - 1ULL);  // bits strictly above k (k=63 -> 0)
        sup_word |= mk & (bit - 1ULL);           // bit==0 -> all-ones, bit==1 -> 0
      }
    }
    // per-lane remv update, gated by uniform keep_word
    u64 acc = 0;
#pragma unroll
    for (int t = 0; t < 64; ++t)
      acc |= ((keep_word >> t) & 1ULL) ? rowv[t] : 0ULL;
    r |= acc;
    if (lane == 0) kwLDS[g] = keep_word;
    nk += __popcll(keep_word);                   // uniform
    if (nk >= POST) break;                       // first 512 keeps found
  }
  __syncthreads();
  // expansion: lane l expands group l's keep word; rank via wave prefix scan
  u64 kw = kwLDS[lane];
  int cnt = __popcll(kw);
  int pfx = cnt;
#pragma unroll
  for (int d = 1; d < 64; d <<= 1) {
    int up = __shfl_up(pfx, d, 64);
    if (lane >= d) pfx += up;
  }
  int total = __shfl(pfx, 63, 64);
  int pos = pfx - cnt;                           // exclusive prefix
  while (kw) {
    int t = __ffsll((long long)kw) - 1;
    kw &= kw - 1;
    if (pos < POST) keepIdx[b * POST + pos] = lane * 64 + t;
    ++pos;
  }
  if (lane == 0) keepCount[b] = total < POST ? total : POST;
}

// Write all 512 slots per batch: kept -> data, empty -> 0 (label 1).
__global__ void output_kernel(const int* __restrict__ keepIdx, const int* __restrict__ keepCount,
                              const float* __restrict__ topBox, const float* __restrict__ topS,
                              const int* __restrict__ topL, float* __restrict__ out) {
  int g = blockIdx.x * blockDim.x + threadIdx.x;
  if (g >= BB * POST) return;
  int b = g >> 9, s = g & (POST - 1);
  float* outR = out;                       // BB*POST*7
  float* outS = out + BB * POST * 7;       // +14336
  float* outL = outS + BB * POST;          // +2048
  int cnt = keepCount[b];
  if (s < cnt) {
    int i = keepIdx[g];
    const float* tb = topBox + ((size_t)(b << 12) + i) * 7;
#pragma unroll
    for (int c = 0; c < 7; ++c) outR[(size_t)g * 7 + c] = tb[c];
    outS[g] = topS[(b << 12) + i];
    outL[g] = (float)(topL[(b << 12) + i] + 1);
  } else {
#pragma unroll
    for (int c = 0; c < 7; ++c) outR[(size_t)g * 7 + c] = 0.0f;
    outS[g] = 0.0f;
    outL[g] = 1.0f;
  }
}

extern "C" void kernel_launch(void* const* d_in, const int* in_sizes, int n_in,
                              void* d_out, int out_size, void* d_ws, size_t ws_size,
                              hipStream_t stream) {
  const float* boxes = (const float*)d_in[0];   // (4,32768,7)
  const float* cls   = (const float*)d_in[1];   // (4,32768,3)
  float* out = (float*)d_out;

  // ---- workspace carve-up (~12.8 MB) ----
  char* p = (char*)d_ws;
  auto take = [&](size_t bytes) { char* r = p; p += (bytes + 255) & ~(size_t)255; return (void*)r; };
  float* scores  = (float*)take((size_t)BB * NN * 4);
  int*   labels  = (int*)  take((size_t)BB * NN * 4);
  u64*   keysA   = (u64*)  take((size_t)BB * NN * 8);
  u64*   keysB   = (u64*)  take((size_t)BB * NN * 8);
  float* topBox  = (float*)take((size_t)BB * PRE * 7 * 4);
  float* X1      = (float*)take((size_t)BB * PRE * 4);
  float* Y1      = (float*)take((size_t)BB * PRE * 4);
  float* X2      = (float*)take((size_t)BB * PRE * 4);
  float* Y2      = (float*)take((size_t)BB * PRE * 4);
  float* AR      = (float*)take((size_t)BB * PRE * 4);
  float* topS    = (float*)take((size_t)BB * PRE * 4);
  int*   topL    = (int*)  take((size_t)BB * PRE * 4);
  u64*   maskBuf = (u64*)  take((size_t)BB * PRE * 64 * 8);
  u64*   diagBuf = (u64*)  take((size_t)BB * PRE * 8);
  int*   keepIdx = (int*)  take((size_t)BB * POST * 4);
  int*   keepCnt = (int*)  take((size_t)BB * 4);

  score_kernel<<<(BB * NN + 255) / 256, 256, 0, stream>>>(cls, scores, labels, keysA);
  sort4k_kernel<<<BB * 8, 512, 0, stream>>>(keysA);
  merge_kernel<<<BB * 4, 1024, 65536, stream>>>(keysA, keysB, 4, 32768, 16384);
  merge_kernel<<<BB * 2, 1024, 65536, stream>>>(keysB, keysA, 2, 16384, 8192);
  merge_kernel<<<BB * 1, 1024, 65536, stream>>>(keysA, keysB, 1, 8192, 4096);
  gather_kernel<<<(BB * PRE + 255) / 256, 256, 0, stream>>>(keysB, boxes, scores, labels,
                                                            topBox, X1, Y1, X2, Y2, AR, topS, topL);
  mask_kernel<<<(BB * PRE * 64 + 255) / 256, 256, 0, stream>>>(X1, Y1, X2, Y2, AR, maskBuf, diagBuf);
  scan_kernel<<<BB, 64, 0, stream>>>(maskBuf, diagBuf, keepIdx, keepCnt);
  output_kernel<<<(BB * POST + 255) / 256, 256, 0, stream>>>(keepIdx, keepCnt, topBox, topS, topL, out);
}